// Round 2
// baseline (86.117 us; speedup 1.0000x reference)
//
#include <hip/hip_runtime.h>

// PointPillarsScatter: scatter [N, C] float32 pillar features into a dense
// canvas [B, C, nz*ny*nx] (nz=1). Round 1 resubmit (infra failure last round):
// memset + scatter, correctness-first.

__global__ void pps_scatter_kernel(const float* __restrict__ vf,
                                   const int* __restrict__ coords,   // [N,4] int32: b,z,y,x
                                   const int* __restrict__ nz_p,
                                   const int* __restrict__ ny_p,
                                   const int* __restrict__ nx_p,
                                   float* __restrict__ out,
                                   int n_points, int C) {
    int idx = blockIdx.x * blockDim.x + threadIdx.x;
    int total = n_points * C;
    if (idx >= total) return;

    int n = idx / C;        // point index
    int c = idx - n * C;    // channel

    int nz = nz_p[0];
    int ny = ny_p[0];
    int nx = nx_p[0];
    long long spatial = (long long)nz * ny * nx;

    int b = coords[4 * n + 0];
    int z = coords[4 * n + 1];
    int y = coords[4 * n + 2];
    int x = coords[4 * n + 3];

    // Faithful to reference: per-sample index = z*nz + y*nx + x  (z==0 here)
    long long s = (long long)z * nz + (long long)y * nx + (long long)x;
    long long o = ((long long)b * C + c) * spatial + s;

    out[o] = vf[idx];
}

extern "C" void kernel_launch(void* const* d_in, const int* in_sizes, int n_in,
                              void* d_out, int out_size, void* d_ws, size_t ws_size,
                              hipStream_t stream) {
    const float* vf     = (const float*)d_in[0];
    const int*   coords = (const int*)d_in[1];
    // d_in[2] = batch_size (unused on host), d_in[3]=nz, d_in[4]=ny, d_in[5]=nx
    const int* nz_p = (const int*)d_in[3];
    const int* ny_p = (const int*)d_in[4];
    const int* nx_p = (const int*)d_in[5];
    float* out = (float*)d_out;

    int n_points = in_sizes[1] / 4;          // coords flat size = N*4
    int C        = in_sizes[0] / n_points;   // voxel_features flat size = N*C

    // Zero the canvas (graph-capture-safe memset node on the stream).
    hipMemsetAsync(d_out, 0, (size_t)out_size * sizeof(float), stream);

    int total = n_points * C;
    int block = 256;
    int grid  = (total + block - 1) / block;
    pps_scatter_kernel<<<grid, block, 0, stream>>>(vf, coords, nz_p, ny_p, nx_p,
                                                   out, n_points, C);
}

// Round 3
// 69.839 us; speedup vs baseline: 1.2331x; 1.2331x over previous
//
#include <hip/hip_runtime.h>

// PointPillarsScatter, round 3: single coalesced output pass via inverse map.
//   pass A: memset int32 index canvas (d_ws) to -1 (3.4 MB)
//   pass B: scatter point-id into index canvas (64k 4B writes)
//   pass C: gather — every output element written once, coalesced float4
// Geometry (B, nz, ny, nx) read from device scalars inside kernels; grid sized
// from out_size only (capture-safe).

__global__ void pps_build_idx(const int* __restrict__ coords,
                              const int* __restrict__ nz_p,
                              const int* __restrict__ ny_p,
                              const int* __restrict__ nx_p,
                              int* __restrict__ idxmap, int n_points) {
    int n = blockIdx.x * blockDim.x + threadIdx.x;
    if (n >= n_points) return;
    int nz = nz_p[0], ny = ny_p[0], nx = nx_p[0];
    int spatial = nz * ny * nx;
    int b = coords[4 * n + 0];
    int z = coords[4 * n + 1];
    int y = coords[4 * n + 2];
    int x = coords[4 * n + 3];
    // faithful to reference: per-sample index = z*nz + y*nx + x
    int cell = b * spatial + z * nz + y * nx + x;
    idxmap[cell] = n;
}

__global__ void pps_gather(const float* __restrict__ vf,
                           const int* __restrict__ idxmap,
                           const int* __restrict__ bsz_p,
                           const int* __restrict__ nz_p,
                           const int* __restrict__ ny_p,
                           const int* __restrict__ nx_p,
                           float* __restrict__ out, int C) {
    const int B = bsz_p[0];
    const int spatial = nz_p[0] * ny_p[0] * nx_p[0];
    const int rows = B * C;                       // one row = one (b,c) plane
    const int quads_per_row = (spatial + 3) >> 2; // float4 quads per plane
    const int blocks_per_row = (quads_per_row + 255) >> 8;
    const long long vblocks = (long long)rows * blocks_per_row;
    const bool aligned = ((spatial & 3) == 0);

    for (long long vb = blockIdx.x; vb < vblocks; vb += gridDim.x) {
        // bc fast, s-tile slow: concurrent blocks share the same s-tile of the
        // index canvas across all (b,c) -> idx + vf tiles stay hot in L2.
        int tile = (int)(vb / rows);
        int bc   = (int)(vb - (long long)tile * rows);
        int b    = bc / C;
        int c    = bc - b * C;
        int q    = (tile << 8) + threadIdx.x;
        if (q >= quads_per_row) continue;
        int s = q << 2;
        long long obase = (long long)bc * spatial;
        long long ibase = (long long)b * spatial;

        if (aligned && s + 3 < spatial) {
            int4 iv = *reinterpret_cast<const int4*>(idxmap + ibase + s);
            float4 o;
            o.x = (iv.x >= 0) ? vf[(long long)iv.x * C + c] : 0.0f;
            o.y = (iv.y >= 0) ? vf[(long long)iv.y * C + c] : 0.0f;
            o.z = (iv.z >= 0) ? vf[(long long)iv.z * C + c] : 0.0f;
            o.w = (iv.w >= 0) ? vf[(long long)iv.w * C + c] : 0.0f;
            *reinterpret_cast<float4*>(out + obase + s) = o;
        } else {
            for (int j = 0; j < 4; ++j) {
                int ss = s + j;
                if (ss >= spatial) break;
                int iv = idxmap[ibase + ss];
                out[obase + ss] = (iv >= 0) ? vf[(long long)iv * C + c] : 0.0f;
            }
        }
    }
}

// -------- fallback path (round-1): memset + direct scatter ----------------
__global__ void pps_scatter_kernel(const float* __restrict__ vf,
                                   const int* __restrict__ coords,
                                   const int* __restrict__ nz_p,
                                   const int* __restrict__ ny_p,
                                   const int* __restrict__ nx_p,
                                   float* __restrict__ out,
                                   int n_points, int C) {
    int idx = blockIdx.x * blockDim.x + threadIdx.x;
    int total = n_points * C;
    if (idx >= total) return;
    int n = idx / C;
    int c = idx - n * C;
    int nz = nz_p[0], ny = ny_p[0], nx = nx_p[0];
    long long spatial = (long long)nz * ny * nx;
    int b = coords[4 * n + 0];
    int z = coords[4 * n + 1];
    int y = coords[4 * n + 2];
    int x = coords[4 * n + 3];
    long long s = (long long)z * nz + (long long)y * nx + (long long)x;
    out[((long long)b * C + c) * spatial + s] = vf[idx];
}

extern "C" void kernel_launch(void* const* d_in, const int* in_sizes, int n_in,
                              void* d_out, int out_size, void* d_ws, size_t ws_size,
                              hipStream_t stream) {
    const float* vf     = (const float*)d_in[0];
    const int*   coords = (const int*)d_in[1];
    const int*   bsz_p  = (const int*)d_in[2];
    const int*   nz_p   = (const int*)d_in[3];
    const int*   ny_p   = (const int*)d_in[4];
    const int*   nx_p   = (const int*)d_in[5];
    float* out = (float*)d_out;

    int n_points = in_sizes[1] / 4;          // coords = [N,4]
    int C        = in_sizes[0] / n_points;   // vf = [N,C]
    long long bspatial = (long long)out_size / C;   // B * spatial
    size_t idx_bytes = (size_t)bspatial * sizeof(int);

    if (ws_size >= idx_bytes) {
        int* idxmap = (int*)d_ws;
        // pass A: index canvas = -1
        hipMemsetAsync(idxmap, 0xFF, idx_bytes, stream);
        // pass B: scatter point ids
        {
            int block = 256;
            int grid = (n_points + block - 1) / block;
            pps_build_idx<<<grid, block, 0, stream>>>(coords, nz_p, ny_p, nx_p,
                                                      idxmap, n_points);
        }
        // pass C: coalesced gather into output (writes every element once)
        {
            int block = 256;
            long long quads = ((long long)out_size + 3) / 4;
            long long g = (quads + block - 1) / block;
            int grid = (int)((g > 0x7FFFFFFF) ? 0x7FFFFFFF : g);
            pps_gather<<<grid, block, 0, stream>>>(vf, idxmap, bsz_p, nz_p, ny_p,
                                                   nx_p, out, C);
        }
    } else {
        // fallback: memset full canvas + direct scatter
        hipMemsetAsync(d_out, 0, (size_t)out_size * sizeof(float), stream);
        int total = n_points * C;
        int block = 256;
        int grid  = (total + block - 1) / block;
        pps_scatter_kernel<<<grid, block, 0, stream>>>(vf, coords, nz_p, ny_p,
                                                       nx_p, out, n_points, C);
    }
}

// Round 5
// 52.604 us; speedup vs baseline: 1.6371x; 1.3276x over previous
//
#include <hip/hip_runtime.h>

// PointPillarsScatter, round 4 resubmit (infra failure): inverse-map gather
// with register-cached index quads. One thread owns 4 cells (int4 of idxmap)
// and loops a 16-channel chunk, emitting one coalesced float4 store per
// channel. idxmap re-read drops 64x -> 4x; vf reads are one 64B line per
// valid cell per chunk.

__global__ void pps_build_idx(const int* __restrict__ coords,
                              const int* __restrict__ nz_p,
                              const int* __restrict__ ny_p,
                              const int* __restrict__ nx_p,
                              int* __restrict__ idxmap, int n_points) {
    int n = blockIdx.x * blockDim.x + threadIdx.x;
    if (n >= n_points) return;
    int nz = nz_p[0], ny = ny_p[0], nx = nx_p[0];
    long long spatial = (long long)nz * ny * nx;
    int b = coords[4 * n + 0];
    int z = coords[4 * n + 1];
    int y = coords[4 * n + 2];
    int x = coords[4 * n + 3];
    // faithful to reference: per-sample index = z*nz + y*nx + x
    long long cell = b * spatial + (long long)z * nz + (long long)y * nx + x;
    idxmap[cell] = n;
}

__global__ __launch_bounds__(256)
void pps_gather_v2(const float* __restrict__ vf,
                   const int* __restrict__ idxmap,
                   const int* __restrict__ nz_p,
                   const int* __restrict__ ny_p,
                   const int* __restrict__ nx_p,
                   float* __restrict__ out,
                   int C, long long ncells, int c_chunk) {
    const long long spatial = (long long)nz_p[0] * ny_p[0] * nx_p[0];
    const long long nquads = (ncells + 3) >> 2;
    const int c0 = blockIdx.y * c_chunk;
    int cn = C - c0;
    if (cn > c_chunk) cn = c_chunk;
    if (cn <= 0) return;

    for (long long q = blockIdx.x * (long long)blockDim.x + threadIdx.x;
         q < nquads; q += (long long)gridDim.x * blockDim.x) {
        long long cell = q << 2;
        long long b = cell / spatial;
        long long s = cell - b * spatial;

        if (cell + 3 < ncells && s + 3 < spatial) {
            // fast path: quad fully inside one sample
            int4 iv = *reinterpret_cast<const int4*>(idxmap + cell);
            // clamp invalid to row 0 -> unconditional load + cndmask, no
            // divergent dual-loop serialization
            const float* px = vf + (long long)(iv.x >= 0 ? iv.x : 0) * C + c0;
            const float* py = vf + (long long)(iv.y >= 0 ? iv.y : 0) * C + c0;
            const float* pz = vf + (long long)(iv.z >= 0 ? iv.z : 0) * C + c0;
            const float* pw = vf + (long long)(iv.w >= 0 ? iv.w : 0) * C + c0;
            float* op = out + (b * C + c0) * spatial + s;
            #pragma unroll 4
            for (int c = 0; c < cn; ++c) {
                float4 o;
                o.x = (iv.x >= 0) ? px[c] : 0.0f;
                o.y = (iv.y >= 0) ? py[c] : 0.0f;
                o.z = (iv.z >= 0) ? pz[c] : 0.0f;
                o.w = (iv.w >= 0) ? pw[c] : 0.0f;
                *reinterpret_cast<float4*>(op) = o;
                op += spatial;
            }
        } else {
            // tail / sample-boundary straddle: scalar per element
            for (int j = 0; j < 4; ++j) {
                long long cc = cell + j;
                if (cc >= ncells) break;
                long long bb = cc / spatial;
                long long ss = cc - bb * spatial;
                int idx = idxmap[cc];
                for (int c = 0; c < cn; ++c)
                    out[(bb * C + c0 + c) * spatial + ss] =
                        (idx >= 0) ? vf[(long long)idx * C + c0 + c] : 0.0f;
            }
        }
    }
}

// -------- fallback path (round-1): memset + direct scatter ----------------
__global__ void pps_scatter_kernel(const float* __restrict__ vf,
                                   const int* __restrict__ coords,
                                   const int* __restrict__ nz_p,
                                   const int* __restrict__ ny_p,
                                   const int* __restrict__ nx_p,
                                   float* __restrict__ out,
                                   int n_points, int C) {
    int idx = blockIdx.x * blockDim.x + threadIdx.x;
    int total = n_points * C;
    if (idx >= total) return;
    int n = idx / C;
    int c = idx - n * C;
    int nz = nz_p[0], ny = ny_p[0], nx = nx_p[0];
    long long spatial = (long long)nz * ny * nx;
    int b = coords[4 * n + 0];
    int z = coords[4 * n + 1];
    int y = coords[4 * n + 2];
    int x = coords[4 * n + 3];
    long long s = (long long)z * nz + (long long)y * nx + (long long)x;
    out[((long long)b * C + c) * spatial + s] = vf[idx];
}

extern "C" void kernel_launch(void* const* d_in, const int* in_sizes, int n_in,
                              void* d_out, int out_size, void* d_ws, size_t ws_size,
                              hipStream_t stream) {
    const float* vf     = (const float*)d_in[0];
    const int*   coords = (const int*)d_in[1];
    const int*   nz_p   = (const int*)d_in[3];
    const int*   ny_p   = (const int*)d_in[4];
    const int*   nx_p   = (const int*)d_in[5];
    float* out = (float*)d_out;

    int n_points = in_sizes[1] / 4;          // coords = [N,4]
    int C        = in_sizes[0] / n_points;   // vf = [N,C]
    long long ncells = (long long)out_size / C;   // B * spatial
    size_t idx_bytes = (size_t)ncells * sizeof(int);

    if (ws_size >= idx_bytes) {
        int* idxmap = (int*)d_ws;
        // pass A: index canvas = -1 (3.4 MB)
        hipMemsetAsync(idxmap, 0xFF, idx_bytes, stream);
        // pass B: scatter point ids (64k 4B writes)
        {
            int block = 256;
            int grid = (n_points + block - 1) / block;
            pps_build_idx<<<grid, block, 0, stream>>>(coords, nz_p, ny_p, nx_p,
                                                      idxmap, n_points);
        }
        // pass C: coalesced gather, idx quads register-cached over c-chunk
        {
            int block = 256;
            int c_chunk = 16;                 // 16 floats = one 64B vf line
            if (c_chunk > C) c_chunk = C;
            long long nquads = (ncells + 3) / 4;
            long long gx = (nquads + block - 1) / block;
            if (gx > 0x7FFFFFFF) gx = 0x7FFFFFFF;
            int gy = (C + c_chunk - 1) / c_chunk;
            dim3 grid((unsigned)gx, (unsigned)gy, 1);
            pps_gather_v2<<<grid, block, 0, stream>>>(vf, idxmap, nz_p, ny_p,
                                                      nx_p, out, C, ncells,
                                                      c_chunk);
        }
    } else {
        // fallback: memset full canvas + direct scatter
        hipMemsetAsync(d_out, 0, (size_t)out_size * sizeof(float), stream);
        int total = n_points * C;
        int block = 256;
        int grid  = (total + block - 1) / block;
        pps_scatter_kernel<<<grid, block, 0, stream>>>(vf, coords, nz_p, ny_p,
                                                       nx_p, out, n_points, C);
    }
}

// Round 6
// 47.963 us; speedup vs baseline: 1.7955x; 1.0968x over previous
//
#include <hip/hip_runtime.h>

// PointPillarsScatter, round 6: inverse-map gather, one thread = one cell-quad
// x all 64 channels. Per 4-channel sub-chunk: conditional float4 vf loads
// (skipped entirely for empty cells ~92.5%) + register transpose + 4 coalesced
// float4 stores. vmem/quad drops ~324 -> ~70; pass becomes HBM-write-bound.

__global__ void pps_build_idx(const int* __restrict__ coords,
                              const int* __restrict__ nz_p,
                              const int* __restrict__ ny_p,
                              const int* __restrict__ nx_p,
                              int* __restrict__ idxmap, int n_points) {
    int n = blockIdx.x * blockDim.x + threadIdx.x;
    if (n >= n_points) return;
    int nz = nz_p[0], ny = ny_p[0], nx = nx_p[0];
    long long spatial = (long long)nz * ny * nx;
    int b = coords[4 * n + 0];
    int z = coords[4 * n + 1];
    int y = coords[4 * n + 2];
    int x = coords[4 * n + 3];
    // faithful to reference: per-sample index = z*nz + y*nx + x
    long long cell = b * spatial + (long long)z * nz + (long long)y * nx + x;
    idxmap[cell] = n;
}

__global__ __launch_bounds__(128)
void pps_gather_v3(const float* __restrict__ vf,
                   const int* __restrict__ idxmap,
                   const int* __restrict__ nz_p,
                   const int* __restrict__ ny_p,
                   const int* __restrict__ nx_p,
                   float* __restrict__ out,
                   int C, long long ncells) {
    const long long spatial = (long long)nz_p[0] * ny_p[0] * nx_p[0];
    const long long nquads = (ncells + 3) >> 2;
    long long q = blockIdx.x * (long long)blockDim.x + threadIdx.x;
    if (q >= nquads) return;

    long long cell = q << 2;
    long long b = cell / spatial;
    long long s = cell - b * spatial;

    if (cell + 3 < ncells && s + 3 < spatial && (C & 3) == 0) {
        // fast path: quad inside one sample, channels divisible by 4
        int4 iv = *reinterpret_cast<const int4*>(idxmap + cell);
        const bool vx = iv.x >= 0, vy = iv.y >= 0, vz = iv.z >= 0, vw = iv.w >= 0;
        const float* px = vf + (long long)iv.x * C;
        const float* py = vf + (long long)iv.y * C;
        const float* pz = vf + (long long)iv.z * C;
        const float* pw = vf + (long long)iv.w * C;
        float* op0 = out + b * (long long)C * spatial + s;

        #pragma unroll 4
        for (int cc = 0; cc < C; cc += 4) {
            float4 rx = make_float4(0.f, 0.f, 0.f, 0.f);
            float4 ry = rx, rz = rx, rw = rx;
            if (vx) rx = *reinterpret_cast<const float4*>(px + cc);
            if (vy) ry = *reinterpret_cast<const float4*>(py + cc);
            if (vz) rz = *reinterpret_cast<const float4*>(pz + cc);
            if (vw) rw = *reinterpret_cast<const float4*>(pw + cc);
            float* op = op0 + (long long)cc * spatial;
            *reinterpret_cast<float4*>(op) = make_float4(rx.x, ry.x, rz.x, rw.x);
            op += spatial;
            *reinterpret_cast<float4*>(op) = make_float4(rx.y, ry.y, rz.y, rw.y);
            op += spatial;
            *reinterpret_cast<float4*>(op) = make_float4(rx.z, ry.z, rz.z, rw.z);
            op += spatial;
            *reinterpret_cast<float4*>(op) = make_float4(rx.w, ry.w, rz.w, rw.w);
        }
    } else {
        // tail / sample-boundary straddle / odd C: scalar per element
        for (int j = 0; j < 4; ++j) {
            long long cc = cell + j;
            if (cc >= ncells) break;
            long long bb = cc / spatial;
            long long ss = cc - bb * spatial;
            int idx = idxmap[cc];
            for (int c = 0; c < C; ++c)
                out[(bb * C + c) * spatial + ss] =
                    (idx >= 0) ? vf[(long long)idx * C + c] : 0.0f;
        }
    }
}

// -------- fallback path (round-1): memset + direct scatter ----------------
__global__ void pps_scatter_kernel(const float* __restrict__ vf,
                                   const int* __restrict__ coords,
                                   const int* __restrict__ nz_p,
                                   const int* __restrict__ ny_p,
                                   const int* __restrict__ nx_p,
                                   float* __restrict__ out,
                                   int n_points, int C) {
    int idx = blockIdx.x * blockDim.x + threadIdx.x;
    int total = n_points * C;
    if (idx >= total) return;
    int n = idx / C;
    int c = idx - n * C;
    int nz = nz_p[0], ny = ny_p[0], nx = nx_p[0];
    long long spatial = (long long)nz * ny * nx;
    int b = coords[4 * n + 0];
    int z = coords[4 * n + 1];
    int y = coords[4 * n + 2];
    int x = coords[4 * n + 3];
    long long s = (long long)z * nz + (long long)y * nx + (long long)x;
    out[((long long)b * C + c) * spatial + s] = vf[idx];
}

extern "C" void kernel_launch(void* const* d_in, const int* in_sizes, int n_in,
                              void* d_out, int out_size, void* d_ws, size_t ws_size,
                              hipStream_t stream) {
    const float* vf     = (const float*)d_in[0];
    const int*   coords = (const int*)d_in[1];
    const int*   nz_p   = (const int*)d_in[3];
    const int*   ny_p   = (const int*)d_in[4];
    const int*   nx_p   = (const int*)d_in[5];
    float* out = (float*)d_out;

    int n_points = in_sizes[1] / 4;          // coords = [N,4]
    int C        = in_sizes[0] / n_points;   // vf = [N,C]
    long long ncells = (long long)out_size / C;   // B * spatial
    size_t idx_bytes = (size_t)ncells * sizeof(int);

    if (ws_size >= idx_bytes) {
        int* idxmap = (int*)d_ws;
        // pass A: index canvas = -1 (3.4 MB)
        hipMemsetAsync(idxmap, 0xFF, idx_bytes, stream);
        // pass B: scatter point ids (64k 4B writes)
        {
            int block = 256;
            int grid = (n_points + block - 1) / block;
            pps_build_idx<<<grid, block, 0, stream>>>(coords, nz_p, ny_p, nx_p,
                                                      idxmap, n_points);
        }
        // pass C: coalesced gather, full-C per thread, vectorized + masked vf
        {
            int block = 128;
            long long nquads = (ncells + 3) / 4;
            long long gx = (nquads + block - 1) / block;
            if (gx > 0x7FFFFFFF) gx = 0x7FFFFFFF;
            pps_gather_v3<<<(int)gx, block, 0, stream>>>(vf, idxmap, nz_p, ny_p,
                                                         nx_p, out, C, ncells);
        }
    } else {
        // fallback: memset full canvas + direct scatter
        hipMemsetAsync(d_out, 0, (size_t)out_size * sizeof(float), stream);
        int total = n_points * C;
        int block = 256;
        int grid  = (total + block - 1) / block;
        pps_scatter_kernel<<<grid, block, 0, stream>>>(vf, coords, nz_p, ny_p,
                                                       nx_p, out, n_points, C);
    }
}